// Round 1
// baseline (5043.481 us; speedup 1.0000x reference)
//
#include <hip/hip_runtime.h>

#define USER_NUM 100000
#define ITEM_NUM 50000
#define NTOT     (USER_NUM + ITEM_NUM)
#define EMB      64
#define GAMMA    0.5f
#define NLAYERS  3
#define EPS      1e-12f

// ---------------------------------------------------------------------------
// out[i] = a * src[i]   (float4-vectorized, grid-stride)
// ---------------------------------------------------------------------------
__global__ void scale_copy_kernel(const float* __restrict__ src,
                                  float* __restrict__ dst,
                                  float a, int n4) {
    int stride = gridDim.x * blockDim.x;
    for (int i = blockIdx.x * blockDim.x + threadIdx.x; i < n4; i += stride) {
        float4 v = reinterpret_cast<const float4*>(src)[i];
        v.x *= a; v.y *= a; v.z *= a; v.w *= a;
        reinterpret_cast<float4*>(dst)[i] = v;
    }
}

// ---------------------------------------------------------------------------
// Row L2-normalize: dst[r] = src[r] / (||src[r]|| + EPS).
// 16 lanes per row, float4 per lane (64 floats per row), shfl_xor reduce
// within the 16-lane group (xor masks 1,2,4,8 stay inside the group).
// ---------------------------------------------------------------------------
__global__ void normalize_kernel(const float* __restrict__ src,
                                 float* __restrict__ dst, int nrows) {
    int tid = blockIdx.x * blockDim.x + threadIdx.x;
    int row = tid >> 4;
    if (row >= nrows) return;
    int l = tid & 15;
    float4 v = reinterpret_cast<const float4*>(src)[(size_t)row * 16 + l];
    float ss = v.x * v.x + v.y * v.y + v.z * v.z + v.w * v.w;
    ss += __shfl_xor(ss, 1);
    ss += __shfl_xor(ss, 2);
    ss += __shfl_xor(ss, 4);
    ss += __shfl_xor(ss, 8);
    float inv = 1.0f / (sqrtf(ss) + EPS);
    v.x *= inv; v.y *= inv; v.z *= inv; v.w *= inv;
    reinterpret_cast<float4*>(dst)[(size_t)row * 16 + l] = v;
}

// ---------------------------------------------------------------------------
// COO SpMM scatter: y[r, :] += v * x[c, :]  for each nonzero.
// One wave (64 lanes) per nonzero; lane = embedding dim. The index loads are
// wave-uniform (single broadcast request); the x load is one coalesced 256 B
// request; one f32 atomicAdd per lane (device-scope, executes at L2).
// ---------------------------------------------------------------------------
__global__ void spmm_scatter_kernel(const int* __restrict__ rows,
                                    const int* __restrict__ cols,
                                    const float* __restrict__ vals,
                                    const float* __restrict__ x,
                                    float* __restrict__ y, int nnz) {
    int lane = threadIdx.x & 63;
    int wave = (blockIdx.x * blockDim.x + threadIdx.x) >> 6;
    int nw   = (gridDim.x * blockDim.x) >> 6;
    for (int i = wave; i < nnz; i += nw) {
        int   r = rows[i];
        int   c = cols[i];
        float v = vals[i];
        float xv = x[(size_t)c * EMB + lane];
        atomicAdd(&y[(size_t)r * EMB + lane], v * xv);
    }
}

// ---------------------------------------------------------------------------
// out[i] += a * x[i]   (float4-vectorized, grid-stride)
// ---------------------------------------------------------------------------
__global__ void axpy_kernel(const float* __restrict__ x,
                            float* __restrict__ out, float a, int n4) {
    int stride = gridDim.x * blockDim.x;
    for (int i = blockIdx.x * blockDim.x + threadIdx.x; i < n4; i += stride) {
        float4 v = reinterpret_cast<const float4*>(x)[i];
        float4 o = reinterpret_cast<float4*>(out)[i];
        o.x += a * v.x; o.y += a * v.y; o.z += a * v.z; o.w += a * v.w;
        reinterpret_cast<float4*>(out)[i] = o;
    }
}

extern "C" void kernel_launch(void* const* d_in, const int* in_sizes, int n_in,
                              void* d_out, int out_size, void* d_ws, size_t ws_size,
                              hipStream_t stream) {
    const float* user_emb = (const float*)d_in[0];
    const float* item_emb = (const float*)d_in[1];
    const int*   rows     = (const int*)d_in[2];
    const int*   cols     = (const int*)d_in[3];
    const float* vals     = (const float*)d_in[4];
    const int    nnz      = in_sizes[2];

    float* out = (float*)d_out;
    float* A   = (float*)d_ws;                    // normalized input  [NTOT*EMB]
    float* B   = A + (size_t)NTOT * EMB;          // SpMM output       [NTOT*EMB]

    const int TOTAL = NTOT * EMB;                 // 9,600,000
    const int T4    = TOTAL / 4;

    // out = GAMMA * ego0  (concat(user_emb, item_emb))
    scale_copy_kernel<<<2048, 256, 0, stream>>>(user_emb, out, GAMMA,
                                                USER_NUM * EMB / 4);
    scale_copy_kernel<<<2048, 256, 0, stream>>>(item_emb, out + (size_t)USER_NUM * EMB,
                                                GAMMA, ITEM_NUM * EMB / 4);

    // Layer-0 normalize reads directly from the (virtually concatenated) inputs.
    normalize_kernel<<<(USER_NUM * 16 + 255) / 256, 256, 0, stream>>>(
        user_emb, A, USER_NUM);
    normalize_kernel<<<(ITEM_NUM * 16 + 255) / 256, 256, 0, stream>>>(
        item_emb, A + (size_t)USER_NUM * EMB, ITEM_NUM);

    const float layer_scale = (1.0f - GAMMA) / NLAYERS;   // 0.5/3

    for (int layer = 0; layer < NLAYERS; ++layer) {
        if (layer > 0) {
            // normalize previous layer's output (B) into A
            normalize_kernel<<<(NTOT * 16 + 255) / 256, 256, 0, stream>>>(B, A, NTOT);
        }
        hipMemsetAsync(B, 0, (size_t)TOTAL * sizeof(float), stream);
        spmm_scatter_kernel<<<8192, 256, 0, stream>>>(rows, cols, vals, A, B, nnz);
        axpy_kernel<<<2048, 256, 0, stream>>>(B, out, layer_scale, T4);
    }
}

// Round 2
// 1633.266 us; speedup vs baseline: 3.0880x; 3.0880x over previous
//
#include <hip/hip_runtime.h>

#define USER_NUM 100000
#define ITEM_NUM 50000
#define NTOT     (USER_NUM + ITEM_NUM)
#define EMB      64
#define GAMMA    0.5f
#define NLAYERS  3
#define EPS      1e-12f

#define SCAN_CHUNK 256
#define NCHUNKS    ((NTOT + SCAN_CHUNK - 1) / SCAN_CHUNK)   // 586

// ===========================================================================
// Fast path: on-device CSR build + gather SpMM (no atomics in the hot loop)
// ===========================================================================

// init: X = normalize(concat(user,item)), out = GAMMA * concat(user,item).
// 16 lanes per row, float4 per lane.
__global__ void init_kernel(const float* __restrict__ user_emb,
                            const float* __restrict__ item_emb,
                            float* __restrict__ X,
                            float* __restrict__ out) {
    int tid = blockIdx.x * blockDim.x + threadIdx.x;
    int row = tid >> 4;
    if (row >= NTOT) return;
    int l = tid & 15;
    const float* src = (row < USER_NUM)
        ? user_emb + (size_t)row * EMB
        : item_emb + (size_t)(row - USER_NUM) * EMB;
    float4 v = reinterpret_cast<const float4*>(src)[l];
    // out = GAMMA * ego0
    float4 o = v; o.x *= GAMMA; o.y *= GAMMA; o.z *= GAMMA; o.w *= GAMMA;
    reinterpret_cast<float4*>(out)[(size_t)row * 16 + l] = o;
    // row L2 norm over the 16-lane group
    float ss = v.x * v.x + v.y * v.y + v.z * v.z + v.w * v.w;
    ss += __shfl_xor(ss, 1);
    ss += __shfl_xor(ss, 2);
    ss += __shfl_xor(ss, 4);
    ss += __shfl_xor(ss, 8);
    float inv = 1.0f / (sqrtf(ss) + EPS);
    v.x *= inv; v.y *= inv; v.z *= inv; v.w *= inv;
    reinterpret_cast<float4*>(X)[(size_t)row * 16 + l] = v;
}

// histogram: counts[r]++ over all nnz
__global__ void hist_kernel(const int* __restrict__ rows, int* __restrict__ counts,
                            int nnz) {
    int stride = gridDim.x * blockDim.x;
    for (int i = blockIdx.x * blockDim.x + threadIdx.x; i < nnz; i += stride)
        atomicAdd(&counts[rows[i]], 1);
}

// scan step A: per-chunk sums
__global__ void scan_sums_kernel(const int* __restrict__ counts,
                                 int* __restrict__ chunk_sums) {
    __shared__ int sdata[SCAN_CHUNK];
    int idx = blockIdx.x * SCAN_CHUNK + threadIdx.x;
    int v = (idx < NTOT) ? counts[idx] : 0;
    sdata[threadIdx.x] = v;
    __syncthreads();
    for (int off = SCAN_CHUNK / 2; off > 0; off >>= 1) {
        if (threadIdx.x < off) sdata[threadIdx.x] += sdata[threadIdx.x + off];
        __syncthreads();
    }
    if (threadIdx.x == 0) chunk_sums[blockIdx.x] = sdata[0];
}

// scan step B: serial exclusive scan of chunk sums (tiny); also writes total
__global__ void scan_offsets_kernel(int* __restrict__ chunk_sums,
                                    int* __restrict__ row_ptr) {
    if (threadIdx.x == 0 && blockIdx.x == 0) {
        int running = 0;
        for (int b = 0; b < NCHUNKS; ++b) {
            int t = chunk_sums[b];
            chunk_sums[b] = running;
            running += t;
        }
        row_ptr[NTOT] = running;   // == nnz
    }
}

// scan step C: intra-chunk exclusive scan + chunk offset -> row_ptr & cursor
__global__ void scan_write_kernel(const int* __restrict__ counts,
                                  const int* __restrict__ chunk_sums,
                                  int* __restrict__ row_ptr,
                                  int* __restrict__ cursor) {
    __shared__ int temp[SCAN_CHUNK];
    int idx = blockIdx.x * SCAN_CHUNK + threadIdx.x;
    int v = (idx < NTOT) ? counts[idx] : 0;
    temp[threadIdx.x] = v;
    __syncthreads();
    for (int off = 1; off < SCAN_CHUNK; off <<= 1) {
        int t = (threadIdx.x >= off) ? temp[threadIdx.x - off] : 0;
        __syncthreads();
        temp[threadIdx.x] += t;
        __syncthreads();
    }
    if (idx < NTOT) {
        int excl = temp[threadIdx.x] - v + chunk_sums[blockIdx.x];
        row_ptr[idx] = excl;
        cursor[idx]  = excl;
    }
}

// scatter {col, val} pairs into CSR order via per-row cursors
__global__ void build_kernel(const int* __restrict__ rows,
                             const int* __restrict__ cols,
                             const float* __restrict__ vals,
                             int* __restrict__ cursor,
                             int2* __restrict__ cv, int nnz) {
    int stride = gridDim.x * blockDim.x;
    for (int i = blockIdx.x * blockDim.x + threadIdx.x; i < nnz; i += stride) {
        int r = rows[i];
        int pos = atomicAdd(&cursor[r], 1);
        cv[pos] = make_int2(cols[i], __float_as_int(vals[i]));
    }
}

// gather SpMM, one wave per row, lane = embedding dim.
//   acc = sum_j val_j * X[col_j][lane]        (X is pre-normalized)
//   out[r] += scale * acc
//   if WRITE_NORM: Y[r] = acc / (||acc|| + EPS)   (input for next layer)
template <int WRITE_NORM>
__global__ void spmm_csr_kernel(const int* __restrict__ row_ptr,
                                const int2* __restrict__ cv,
                                const float* __restrict__ X,
                                float* __restrict__ Y,
                                float* __restrict__ out,
                                float scale) {
    int wave = (blockIdx.x * blockDim.x + threadIdx.x) >> 6;
    if (wave >= NTOT) return;
    int lane = threadIdx.x & 63;
    int start = row_ptr[wave];
    int end   = row_ptr[wave + 1];
    float acc = 0.0f;
#pragma unroll 4
    for (int j = start; j < end; ++j) {
        int2 cvj = cv[j];
        float v  = __int_as_float(cvj.y);
        acc += v * X[(size_t)cvj.x * EMB + lane];
    }
    size_t o = (size_t)wave * EMB + lane;
    out[o] += scale * acc;
    if (WRITE_NORM) {
        float ss = acc * acc;
        ss += __shfl_xor(ss, 1);
        ss += __shfl_xor(ss, 2);
        ss += __shfl_xor(ss, 4);
        ss += __shfl_xor(ss, 8);
        ss += __shfl_xor(ss, 16);
        ss += __shfl_xor(ss, 32);
        float inv = 1.0f / (sqrtf(ss) + EPS);
        Y[o] = acc * inv;
    }
}

// ===========================================================================
// Fallback path (round-1 proven kernels) — used if ws_size is too small
// ===========================================================================

__global__ void scale_copy_kernel(const float* __restrict__ src,
                                  float* __restrict__ dst, float a, int n4) {
    int stride = gridDim.x * blockDim.x;
    for (int i = blockIdx.x * blockDim.x + threadIdx.x; i < n4; i += stride) {
        float4 v = reinterpret_cast<const float4*>(src)[i];
        v.x *= a; v.y *= a; v.z *= a; v.w *= a;
        reinterpret_cast<float4*>(dst)[i] = v;
    }
}

__global__ void normalize_kernel(const float* __restrict__ src,
                                 float* __restrict__ dst, int nrows) {
    int tid = blockIdx.x * blockDim.x + threadIdx.x;
    int row = tid >> 4;
    if (row >= nrows) return;
    int l = tid & 15;
    float4 v = reinterpret_cast<const float4*>(src)[(size_t)row * 16 + l];
    float ss = v.x * v.x + v.y * v.y + v.z * v.z + v.w * v.w;
    ss += __shfl_xor(ss, 1);
    ss += __shfl_xor(ss, 2);
    ss += __shfl_xor(ss, 4);
    ss += __shfl_xor(ss, 8);
    float inv = 1.0f / (sqrtf(ss) + EPS);
    v.x *= inv; v.y *= inv; v.z *= inv; v.w *= inv;
    reinterpret_cast<float4*>(dst)[(size_t)row * 16 + l] = v;
}

__global__ void spmm_scatter_kernel(const int* __restrict__ rows,
                                    const int* __restrict__ cols,
                                    const float* __restrict__ vals,
                                    const float* __restrict__ x,
                                    float* __restrict__ y, int nnz) {
    int lane = threadIdx.x & 63;
    int wave = (blockIdx.x * blockDim.x + threadIdx.x) >> 6;
    int nw   = (gridDim.x * blockDim.x) >> 6;
    for (int i = wave; i < nnz; i += nw) {
        int   r = rows[i];
        int   c = cols[i];
        float v = vals[i];
        float xv = x[(size_t)c * EMB + lane];
        atomicAdd(&y[(size_t)r * EMB + lane], v * xv);
    }
}

__global__ void axpy_kernel(const float* __restrict__ x,
                            float* __restrict__ out, float a, int n4) {
    int stride = gridDim.x * blockDim.x;
    for (int i = blockIdx.x * blockDim.x + threadIdx.x; i < n4; i += stride) {
        float4 v = reinterpret_cast<const float4*>(x)[i];
        float4 o = reinterpret_cast<float4*>(out)[i];
        o.x += a * v.x; o.y += a * v.y; o.z += a * v.z; o.w += a * v.w;
        reinterpret_cast<float4*>(out)[i] = o;
    }
}

// ===========================================================================

extern "C" void kernel_launch(void* const* d_in, const int* in_sizes, int n_in,
                              void* d_out, int out_size, void* d_ws, size_t ws_size,
                              hipStream_t stream) {
    const float* user_emb = (const float*)d_in[0];
    const float* item_emb = (const float*)d_in[1];
    const int*   rows     = (const int*)d_in[2];
    const int*   cols     = (const int*)d_in[3];
    const float* vals     = (const float*)d_in[4];
    const int    nnz      = in_sizes[2];

    float* out = (float*)d_out;
    const int TOTAL = NTOT * EMB;                  // 9,600,000 floats
    const float layer_scale = (1.0f - GAMMA) / NLAYERS;

    // ---- workspace layout (fast path) ----
    // X, Y: TOTAL floats each; cv: nnz int2; row_ptr: NTOT+1; cursor: NTOT;
    // chunk_sums: NCHUNKS
    size_t need = (size_t)TOTAL * 4 * 2
                + (size_t)nnz * 8
                + (size_t)(NTOT + 1) * 4
                + (size_t)NTOT * 4
                + (size_t)NCHUNKS * 4
                + 1024;  // alignment slack

    if (ws_size >= need) {
        char* p = (char*)d_ws;
        float* X       = (float*)p;                 p += (size_t)TOTAL * 4;
        float* Y       = (float*)p;                 p += (size_t)TOTAL * 4;
        int2*  cv      = (int2*)p;                  p += (size_t)nnz * 8;
        int*   row_ptr = (int*)p;                   p += (size_t)(NTOT + 1) * 4;
        int*   cursor  = (int*)p;                   p += (size_t)NTOT * 4;
        int*   chunks  = (int*)p;

        // init: X = normalize(ego), out = GAMMA*ego
        init_kernel<<<(NTOT * 16 + 255) / 256, 256, 0, stream>>>(
            user_emb, item_emb, X, out);

        // CSR build
        hipMemsetAsync(cursor, 0, (size_t)NTOT * 4, stream);       // counts
        hist_kernel<<<(nnz + 255) / 256, 256, 0, stream>>>(rows, cursor, nnz);
        scan_sums_kernel<<<NCHUNKS, SCAN_CHUNK, 0, stream>>>(cursor, chunks);
        scan_offsets_kernel<<<1, 64, 0, stream>>>(chunks, row_ptr);
        scan_write_kernel<<<NCHUNKS, SCAN_CHUNK, 0, stream>>>(cursor, chunks,
                                                              row_ptr, cursor);
        build_kernel<<<(nnz + 255) / 256, 256, 0, stream>>>(rows, cols, vals,
                                                            cursor, cv, nnz);

        // 3 fused layers: SpMM + out-accumulate + (normalize for next layer)
        const int SPMM_BLOCKS = (NTOT * 64 + 255) / 256;
        spmm_csr_kernel<1><<<SPMM_BLOCKS, 256, 0, stream>>>(
            row_ptr, cv, X, Y, out, layer_scale);
        spmm_csr_kernel<1><<<SPMM_BLOCKS, 256, 0, stream>>>(
            row_ptr, cv, Y, X, out, layer_scale);
        spmm_csr_kernel<0><<<SPMM_BLOCKS, 256, 0, stream>>>(
            row_ptr, cv, X, Y, out, layer_scale);
        return;
    }

    // ---- fallback: round-1 scatter path (needs 2*TOTAL floats) ----
    float* A = (float*)d_ws;
    float* B = A + (size_t)TOTAL;
    const int T4 = TOTAL / 4;

    scale_copy_kernel<<<2048, 256, 0, stream>>>(user_emb, out, GAMMA,
                                                USER_NUM * EMB / 4);
    scale_copy_kernel<<<2048, 256, 0, stream>>>(item_emb, out + (size_t)USER_NUM * EMB,
                                                GAMMA, ITEM_NUM * EMB / 4);
    normalize_kernel<<<(USER_NUM * 16 + 255) / 256, 256, 0, stream>>>(
        user_emb, A, USER_NUM);
    normalize_kernel<<<(ITEM_NUM * 16 + 255) / 256, 256, 0, stream>>>(
        item_emb, A + (size_t)USER_NUM * EMB, ITEM_NUM);

    for (int layer = 0; layer < NLAYERS; ++layer) {
        if (layer > 0)
            normalize_kernel<<<(NTOT * 16 + 255) / 256, 256, 0, stream>>>(B, A, NTOT);
        hipMemsetAsync(B, 0, (size_t)TOTAL * sizeof(float), stream);
        spmm_scatter_kernel<<<8192, 256, 0, stream>>>(rows, cols, vals, A, B, nnz);
        axpy_kernel<<<2048, 256, 0, stream>>>(B, out, layer_scale, T4);
    }
}